// Round 1
// baseline (43.695 us; speedup 1.0000x reference)
//
#include <hip/hip_runtime.h>
#include <hip/hip_bf16.h>

// DataTerm layer: out[b,h,w,:] = {u,v} - ALPHA * dataTerm * {dI1_dy, dI1_dx}
// where dataTerm = bilinear_sample(I1, normalized-coords-misused-as-pixels) - I2.
// Faithful to the reference's quirks:
//  - _image_gradients returns (dy, dx) and the reference binds them as
//    (grad_x, grad_y), so u uses the ROW diff and v uses the COL diff.
//  - _warp_image normalizes coords to [-1,1] and the sampler treats them as
//    raw pixel coords (floor -> +1 -> clip -> weights from clipped corners,
//    unclipped x,y). All gather indices land in {0,1,2} -> cache-resident.

#define ALPHA 0.1f

constexpr int B = 32, H = 512, W = 512;

__global__ __launch_bounds__(256) void dataterm_kernel(
    const float* __restrict__ I1,
    const float* __restrict__ I2,
    const float* __restrict__ flow,
    float* __restrict__ out)
{
    // One thread handles 4 consecutive-w pixels.
    int tid = blockIdx.x * blockDim.x + threadIdx.x;   // 0 .. B*H*W/4-1
    int w4 = (tid & (W/4 - 1)) * 4;                    // W/4 = 128 groups/row
    int hb = tid >> 7;                                 // tid / (W/4)
    int h  = hb & (H - 1);
    int b  = hb >> 9;                                  // hb / H

    const float* I1b = I1 + (size_t)b * H * W;
    size_t rowoff = (size_t)hb * W + w4;               // (b*H + h)*W + w4

    float4 i1v = *(const float4*)(I1 + rowoff);
    float4 i2v = *(const float4*)(I2 + rowoff);
    float4 i1dn = make_float4(0.f, 0.f, 0.f, 0.f);
    bool has_dn = (h < H - 1);
    if (has_dn) i1dn = *(const float4*)(I1 + rowoff + W);
    float i1r4 = (w4 + 4 < W) ? I1[rowoff + 4] : 0.0f;

    float4 f0 = *(const float4*)(flow + 2 * rowoff);       // u0 v0 u1 v1
    float4 f1 = *(const float4*)(flow + 2 * rowoff + 4);   // u2 v2 u3 v3

    float uarr[4]  = { f0.x, f0.z, f1.x, f1.z };
    float varr[4]  = { f0.y, f0.w, f1.y, f1.w };
    float i1a[5]   = { i1v.x, i1v.y, i1v.z, i1v.w, i1r4 };
    float i1d[4]   = { i1dn.x, i1dn.y, i1dn.z, i1dn.w };
    float i2a[4]   = { i2v.x, i2v.y, i2v.z, i2v.w };

    const float sx = 2.0f / (W - 1.0f);
    const float sy = 2.0f / (H - 1.0f);

    float on[8];
#pragma unroll
    for (int j = 0; j < 4; ++j) {
        int w = w4 + j;
        float u = uarr[j], v = varr[j];
        // normalized coords (then misused as pixel coords, per reference)
        float x = ((float)w + 0.5f * u) * sx - 1.0f;
        float y = ((float)h + 0.5f * v) * sy - 1.0f;
        float x0f = floorf(x), y0f = floorf(y);
        float x1f = x0f + 1.0f, y1f = y0f + 1.0f;
        x0f = fminf(fmaxf(x0f, 0.0f), W - 1.0f);
        x1f = fminf(fmaxf(x1f, 0.0f), W - 1.0f);
        y0f = fminf(fmaxf(y0f, 0.0f), H - 1.0f);
        y1f = fminf(fmaxf(y1f, 0.0f), H - 1.0f);
        int x0i = (int)x0f, x1i = (int)x1f;
        int y0i = (int)y0f, y1i = (int)y1f;
        // gathers: indices in {0,1,2} -> a handful of hot cache lines/batch
        float Ia  = I1b[y0i * W + x0i];
        float Ibv = I1b[y1i * W + x0i];
        float Ic  = I1b[y0i * W + x1i];
        float Id  = I1b[y1i * W + x1i];
        float wa = (x1f - x) * (y1f - y);
        float wb = (x1f - x) * (y - y0f);
        float wc = (x - x0f) * (y1f - y);
        float wd = (x - x0f) * (y - y0f);
        float warped = wa * Ia + wb * Ibv + wc * Ic + wd * Id;
        float dt = warped - i2a[j];
        float gdy = has_dn ? (i1d[j] - i1a[j]) : 0.0f;       // row diff -> u
        float gdx = (w < W - 1) ? (i1a[j + 1] - i1a[j]) : 0.0f; // col diff -> v
        on[2 * j]     = u - ALPHA * dt * gdy;
        on[2 * j + 1] = v - ALPHA * dt * gdx;
    }

    *(float4*)(out + 2 * rowoff)     = make_float4(on[0], on[1], on[2], on[3]);
    *(float4*)(out + 2 * rowoff + 4) = make_float4(on[4], on[5], on[6], on[7]);
}

extern "C" void kernel_launch(void* const* d_in, const int* in_sizes, int n_in,
                              void* d_out, int out_size, void* d_ws, size_t ws_size,
                              hipStream_t stream) {
    const float* I1   = (const float*)d_in[0];
    const float* I2   = (const float*)d_in[1];
    const float* flow = (const float*)d_in[2];
    float* out = (float*)d_out;

    int total_threads = B * H * (W / 4);           // 2,097,152
    int block = 256;
    int grid = total_threads / block;              // 8192
    dataterm_kernel<<<grid, block, 0, stream>>>(I1, I2, flow, out);
}

// Round 2
// 36.110 us; speedup vs baseline: 1.2100x; 1.2100x over previous
//
#include <hip/hip_runtime.h>
#include <hip/hip_bf16.h>

// DataTerm layer: out[b,h,w,:] = {u,v} - ALPHA * dataTerm * {dI1_dy, dI1_dx}
// where dataTerm = bilinear_sample(I1, normalized-coords-misused-as-pixels) - I2.
// Faithful to the reference's quirks:
//  - _image_gradients returns (dy, dx) bound as (grad_x, grad_y): u uses the
//    ROW diff, v uses the COL diff.
//  - _warp_image normalizes coords to [-1,1] and the sampler treats them as
//    raw pixel coords (floor -> +1 -> clip -> weights from clipped corners,
//    unclipped x,y). Hence every gather index lands in {0,1,2}: the sampler
//    only ever touches the 3x3 top-left corner patch of each batch image.
//    We preload those 9 block-uniform values (scalar loads) and select with
//    v_cndmask instead of doing 4 data-dependent gathers per pixel —
//    removes the serial load->addr->gather latency chain (round-1 diagnosis:
//    latency-bound, VALUBusy 17%, HBM 58%).

#define ALPHA 0.1f

constexpr int B = 32, H = 512, W = 512;

__global__ __launch_bounds__(256) void dataterm_kernel(
    const float* __restrict__ I1,
    const float* __restrict__ I2,
    const float* __restrict__ flow,
    float* __restrict__ out)
{
    // 256 blocks per batch image (H*W/4/256); b is wave-uniform -> s_loads.
    int b   = blockIdx.x >> 8;
    int idx = ((blockIdx.x & 255) << 8) | threadIdx.x;  // pixel-group in image
    int w4  = (idx & (W / 4 - 1)) * 4;
    int h   = idx >> 7;

    const float* I1b = I1 + (size_t)b * (H * W);
    // Block-uniform 3x3 corner patch (all bilinear corners live here).
    float S00 = I1b[0],     S01 = I1b[1],         S02 = I1b[2];
    float S10 = I1b[W],     S11 = I1b[W + 1],     S12 = I1b[W + 2];
    float S20 = I1b[2 * W], S21 = I1b[2 * W + 1], S22 = I1b[2 * W + 2];

    size_t rowoff = (size_t)(b * H + h) * W + w4;

    float4 i1v = *(const float4*)(I1 + rowoff);
    float4 i2v = *(const float4*)(I2 + rowoff);
    float4 i1dn = make_float4(0.f, 0.f, 0.f, 0.f);
    bool has_dn = (h < H - 1);
    if (has_dn) i1dn = *(const float4*)(I1 + rowoff + W);
    float i1r4 = (w4 + 4 < W) ? I1[rowoff + 4] : 0.0f;

    float4 f0 = *(const float4*)(flow + 2 * rowoff);       // u0 v0 u1 v1
    float4 f1 = *(const float4*)(flow + 2 * rowoff + 4);   // u2 v2 u3 v3

    float uarr[4] = { f0.x, f0.z, f1.x, f1.z };
    float varr[4] = { f0.y, f0.w, f1.y, f1.w };
    float i1a[5]  = { i1v.x, i1v.y, i1v.z, i1v.w, i1r4 };
    float i1d[4]  = { i1dn.x, i1dn.y, i1dn.z, i1dn.w };
    float i2a[4]  = { i2v.x, i2v.y, i2v.z, i2v.w };

    const float sx = 2.0f / (W - 1.0f);
    const float sy = 2.0f / (H - 1.0f);

    float on[8];
#pragma unroll
    for (int j = 0; j < 4; ++j) {
        int w = w4 + j;
        float u = uarr[j], v = varr[j];
        float x = ((float)w + 0.5f * u) * sx - 1.0f;
        float y = ((float)h + 0.5f * v) * sy - 1.0f;
        float x0f = floorf(x), y0f = floorf(y);
        float x1f = x0f + 1.0f, y1f = y0f + 1.0f;
        x0f = fminf(fmaxf(x0f, 0.0f), W - 1.0f);
        x1f = fminf(fmaxf(x1f, 0.0f), W - 1.0f);
        y0f = fminf(fmaxf(y0f, 0.0f), H - 1.0f);
        y1f = fminf(fmaxf(y1f, 0.0f), H - 1.0f);
        int x0i = (int)x0f, x1i = (int)x1f;   // x0i,y0i in {0,1}; x1i,y1i in {0,1,2}
        int y0i = (int)y0f, y1i = (int)y1f;

        // Select corner values from the preloaded 3x3 patch (pure VALU).
        float r0 = (x0i == 0) ? S00 : S01;
        float r1 = (x0i == 0) ? S10 : S11;
        float r2 = (x0i == 0) ? S20 : S21;
        float q0 = (x1i == 0) ? S00 : ((x1i == 1) ? S01 : S02);
        float q1 = (x1i == 0) ? S10 : ((x1i == 1) ? S11 : S12);
        float q2 = (x1i == 0) ? S20 : ((x1i == 1) ? S21 : S22);
        float Ia  = (y0i == 0) ? r0 : r1;
        float Ibv = (y1i == 0) ? r0 : ((y1i == 1) ? r1 : r2);
        float Ic  = (y0i == 0) ? q0 : q1;
        float Id  = (y1i == 0) ? q0 : ((y1i == 1) ? q1 : q2);

        float wa = (x1f - x) * (y1f - y);
        float wb = (x1f - x) * (y - y0f);
        float wc = (x - x0f) * (y1f - y);
        float wd = (x - x0f) * (y - y0f);
        float warped = wa * Ia + wb * Ibv + wc * Ic + wd * Id;
        float dt = warped - i2a[j];
        float gdy = has_dn ? (i1d[j] - i1a[j]) : 0.0f;          // row diff -> u
        float gdx = (w < W - 1) ? (i1a[j + 1] - i1a[j]) : 0.0f; // col diff -> v
        on[2 * j]     = u - ALPHA * dt * gdy;
        on[2 * j + 1] = v - ALPHA * dt * gdx;
    }

    *(float4*)(out + 2 * rowoff)     = make_float4(on[0], on[1], on[2], on[3]);
    *(float4*)(out + 2 * rowoff + 4) = make_float4(on[4], on[5], on[6], on[7]);
}

extern "C" void kernel_launch(void* const* d_in, const int* in_sizes, int n_in,
                              void* d_out, int out_size, void* d_ws, size_t ws_size,
                              hipStream_t stream) {
    const float* I1   = (const float*)d_in[0];
    const float* I2   = (const float*)d_in[1];
    const float* flow = (const float*)d_in[2];
    float* out = (float*)d_out;

    int total_threads = B * H * (W / 4);           // 2,097,152
    int block = 256;
    int grid = total_threads / block;              // 8192
    dataterm_kernel<<<grid, block, 0, stream>>>(I1, I2, flow, out);
}